// Round 7
// baseline (2121.325 us; speedup 1.0000x reference)
//
#include <hip/hip_runtime.h>
#include <hip/hip_fp16.h>
#include <cstdint>
#include <cstring>

// VQR circuit simulator: 16 qubits, B=512, 4 layers.
// CNOTs are GF(2) index-relabeling bookkeeping. Fused 1q gates (SU(2)) are
// XOR-mask pair rotations. Compile-time schedule (constexpr) as R4.
// NEW vs R4: WAVE-RESIDENT TILE. 64-thread blocks (one wave) hold the whole
// 4096-amp tile in VGPRs (64 amps/lane). Per pass a GF(2) basis B (6 gate
// masks complementing the 6 lane bits) maps the tile; gates with mask in
// span(B) are pure register-pair rotations; others use ds_bpermute
// (lane-xor beta) -- no LDS amp array, ZERO barriers. p/q side asymmetry
// folds into the sign xors (q-side adds kappa^1). Global I/O: per-reg
// coalesced dwords (XOR perm within aligned 256B). MODE0 builds the
// product state in natural coords (in-register butterfly) then permutes
// to B-coords via 64 bpermutes along permutation cycles.

struct GateR {
    uint64_t sgn;        // per-reg sign-select bit (static part, incl. side flip)
    uint8_t  alpha;      // reg-xor (6b)
    uint8_t  beta;       // lane-xor (6b)
    uint8_t  pvmask;     // reg pivot mask if alpha!=0 else 0
    uint8_t  row_lane;   // lane R mask (6b, incl. kappa fold for alpha==0)
    uint8_t  nl;         // chunk R mask (4b)
    uint8_t  gidx;       // coefficient index l*16+w
    uint8_t  pad0, pad1;
};
struct TOp { uint8_t dst, src, lx, flags; };   // flags: 1=saveTmp, 2=useTmp

struct PassR {
    int      ngates;
    GateR    g[24];
    uint16_t EB[64];           // scatter(Brc[r]) -- global-index xor per reg
    int      ntops;
    TOp      tops[64];         // natural->B permutation (pass 0 only)
    uint8_t  gap[4];           // non-local bit positions, ASCENDING (all >=8)
    uint8_t  nlw[4];           // chunk bit k -> wire
    uint8_t  wire_of_bit[12];  // packed local bit -> wire
    uint16_t meas_row;         // measurement parity mask (12 local bits)
    uint8_t  meas_nl;          // measurement parity mask (chunk bits)
    uint64_t measSgn;          // per-reg static measurement sign
};
struct Sched { int np; PassR ps[8]; };

// ---------------- compile-time schedule builder ----------------
constexpr Sched build_sched() {
    Sched S{};
    const int MAXP = 8;
    uint16_t D[16]{}, R[16]{};
    for (int w = 0; w < 16; ++w) { D[w] = R[w] = (uint16_t)(1u << w); }
    uint16_t gD[48]{}, gR[48]{}; uint8_t ggi[48]{}; bool gk[48]{};
    int ng = 0;
    for (int l = 1; l <= 3; ++l) {
        for (int w = 0; w < 16; ++w) { int t = (w + 1) & 15; D[w] ^= D[t]; R[t] ^= R[w]; }
        for (int w = 0; w < 16; ++w) {
            gD[ng] = D[w]; gR[ng] = R[w]; ggi[ng] = (uint8_t)(l * 16 + w);
            gk[ng] = true; ++ng;
        }
    }
    for (int w = 0; w < 16; ++w) { int t = (w + 1) & 15; D[w] ^= D[t]; R[t] ^= R[w]; }
    const uint16_t Rmeas = R[0];
    {   // backward prune
        uint16_t keptD[49]{}, keptR[49]{}; int nk = 0;
        keptD[nk] = 0; keptR[nk] = Rmeas; ++nk;
        for (int i = ng - 1; i >= 0; --i) {
            bool comm = true;
            for (int k = 0; k < nk; ++k) {
                if (__builtin_parity((unsigned)(gD[i] & keptR[k])) ||
                    __builtin_parity((unsigned)(keptD[k] & gR[i]))) { comm = false; break; }
            }
            if (comm) gk[i] = false;
            else { keptD[nk] = gD[i]; keptR[nk] = gR[i]; ++nk; }
        }
    }
    int nkept = 0; unsigned long long keptM = 0;
    for (int i = 0; i < ng; ++i) if (gk[i]) { ++nkept; keptM |= 1ull << i; }
    unsigned long long cm[48]{};
    for (int i = 0; i < ng; ++i)
        for (int j = 0; j < ng; ++j)
            if (!(__builtin_parity((unsigned)(gD[i] & gR[j])) ||
                  __builtin_parity((unsigned)(gD[j] & gR[i]))))
                cm[i] |= 1ull << j;
    int passOf[48]{};
    for (int i = 0; i < ng; ++i) passOf[i] = -1;
    auto bitsim = [&](uint16_t SA_, uint16_t SB_, int maxnp, int* po) -> int {
        unsigned long long sc = 0; int rem = nkept, npp = 0, stall = 0;
        while (rem > 0 && npp < MAXP) {
            uint16_t Sm = (npp & 1) ? SB_ : SA_;
            int got = 0;
            for (int i = 0; i < ng; ++i) {
                unsigned long long bi = 1ull << i;
                if (!(keptM & bi) || (sc & bi)) continue;
                if (gD[i] & Sm) continue;
                unsigned long long prior = keptM & ~sc & (bi - 1ull);
                if (prior & ~cm[i]) continue;
                sc |= bi; --rem; ++got;
                if (po) po[i] = npp;
            }
            ++npp;
            if (!got) { if (++stall >= 2) break; } else stall = 0;
            if (rem > 0 && npp >= maxnp) return 99;
        }
        return rem == 0 ? npp : 99;
    };
    int bestA = -1, bestB = 0;
    for (int target = 2; target <= MAXP && bestA < 0; ++target)
        for (int a = 0; a < 16 && bestA < 0; ++a)
            for (int b = 0; b < 16; ++b) {
                uint16_t SA_ = 0, SB_ = 0;
                for (int k = 0; k < 4; ++k) {
                    SA_ |= (uint16_t)(1u << ((a + k) & 15));
                    SB_ |= (uint16_t)(1u << ((b + k) & 15));
                }
                int rv = bitsim(SA_, SB_, target, nullptr);
                if (rv <= target) { bestA = a; bestB = b; break; }
            }
    if (bestA < 0) { bestA = 0; bestB = 8; }
    uint16_t SA = 0, SB = 0;
    int exA[4]{}, exB[4]{};
    for (int k = 0; k < 4; ++k) {
        exA[k] = (bestA + k) & 15; exB[k] = (bestB + k) & 15;
        SA |= (uint16_t)(1u << exA[k]); SB |= (uint16_t)(1u << exB[k]);
    }
    int np = bitsim(SA, SB, MAXP, passOf);
    if (np > MAXP) np = MAXP;
    if (np < 2) np = 2;
    int wireToPos[16]{}; bool used[16]{};
    int pos = 15;
    for (int k = 0; k < 4; ++k) { wireToPos[exA[k]] = pos--; used[exA[k]] = true; }
    for (int k = 0; k < 4; ++k)
        if (!used[exB[k]]) { wireToPos[exB[k]] = pos--; used[exB[k]] = true; }
    for (int w = 0; w < 16; ++w) if (!used[w]) wireToPos[w] = pos--;
    int posToWire[16]{};
    for (int w = 0; w < 16; ++w) posToWire[wireToPos[w]] = w;
    for (int p = 0; p < np; ++p) {
        PassR& M = S.ps[p];
        const int* ex = (p & 1) ? exB : exA;
        int gp[4]{}, gw[4]{};
        for (int k = 0; k < 4; ++k) { gp[k] = wireToPos[ex[k]]; gw[k] = ex[k]; }
        for (int a2 = 0; a2 < 4; ++a2)
            for (int b2 = a2 + 1; b2 < 4; ++b2)
                if (gp[b2] < gp[a2]) {
                    int t = gp[a2]; gp[a2] = gp[b2]; gp[b2] = t;
                    t = gw[a2]; gw[a2] = gw[b2]; gw[b2] = t;
                }
        for (int k = 0; k < 4; ++k) { M.gap[k] = (uint8_t)gp[k]; M.nlw[k] = (uint8_t)gw[k]; }
        int packedOfWire[16]{};
        for (int w = 0; w < 16; ++w) packedOfWire[w] = -1;
        int t = 0;
        for (int q = 0; q < 16; ++q) {
            bool isgap = false;
            for (int k = 0; k < 4; ++k) if (q == gp[k]) isgap = true;
            if (isgap) continue;
            M.wire_of_bit[t] = (uint8_t)posToWire[q];
            packedOfWire[posToWire[q]] = t;
            ++t;
        }
        uint16_t lm[48]{}, lr[48]{}; uint8_t lnl[48]{}, lgx[48]{}; int nsel = 0;
        for (int i = 0; i < ng; ++i) {
            if (!gk[i] || passOf[i] != p) continue;
            uint16_t m = 0, r = 0; uint8_t nl = 0;
            for (int w = 0; w < 16; ++w) {
                if ((gD[i] >> w) & 1) m |= (uint16_t)(1u << packedOfWire[w]);
                if (((gR[i] >> w) & 1) && packedOfWire[w] >= 0)
                    r |= (uint16_t)(1u << packedOfWire[w]);
            }
            for (int k = 0; k < 4; ++k)
                if ((gR[i] >> gw[k]) & 1) nl |= (uint8_t)(1u << k);
            lm[nsel] = m; lr[nsel] = r; lnl[nsel] = nl; lgx[nsel] = ggi[i]; ++nsel;
        }
        // ---- basis B: 6 gate masks with independent high parts; pad units ----
        uint16_t Bv[6]{}; uint8_t hred[6]{}; int hpiv[6]{}; uint8_t hcmb[6]{}; int nb = 0;
        for (int i = 0; i < nsel && nb < 6; ++i) {
            uint8_t h = (uint8_t)(lm[i] >> 6); uint8_t cb = 0;
            for (int j = 0; j < nb; ++j)
                if ((h >> hpiv[j]) & 1) { h ^= hred[j]; cb ^= hcmb[j]; }
            if (h) {
                hred[nb] = h; hpiv[nb] = 31 - __builtin_clz((unsigned)h);
                hcmb[nb] = (uint8_t)((1u << nb) | cb); Bv[nb] = lm[i]; ++nb;
            }
        }
        for (int b = 5; b >= 0 && nb < 6; --b) {
            uint8_t h = (uint8_t)(1u << b); uint8_t cb = 0;
            for (int j = 0; j < nb; ++j)
                if ((h >> hpiv[j]) & 1) { h ^= hred[j]; cb ^= hcmb[j]; }
            if (h) {
                hred[nb] = h; hpiv[nb] = 31 - __builtin_clz((unsigned)h);
                hcmb[nb] = (uint8_t)((1u << nb) | cb); Bv[nb] = (uint16_t)(1u << (6 + b)); ++nb;
            }
        }
        uint16_t Brc[64]{};
        for (int r = 0; r < 64; ++r) {
            uint16_t v = 0;
            for (int j = 0; j < 6; ++j) if ((r >> j) & 1) v ^= Bv[j];
            Brc[r] = v;
        }
        auto scat = [&](uint16_t x) -> uint16_t {
            unsigned v = x;
            for (int k = 0; k < 4; ++k) {
                unsigned g2 = M.gap[k];
                v = ((v >> g2) << (g2 + 1)) | (v & ((1u << g2) - 1u));
            }
            return (uint16_t)v;
        };
        for (int r = 0; r < 64; ++r) M.EB[r] = scat(Brc[r]);
        // ---- gates ----
        M.ngates = nsel;
        for (int i = 0; i < nsel; ++i) {
            GateR& G = M.g[i];
            uint16_t m = lm[i], row = lr[i];
            uint8_t y = (uint8_t)(m >> 6); uint8_t al = 0;
            for (int j = 0; j < 6; ++j)
                if ((y >> hpiv[j]) & 1) { y ^= hred[j]; al ^= hcmb[j]; }
            uint16_t bt16 = m;
            for (int j = 0; j < 6; ++j) if ((al >> j) & 1) bt16 ^= Bv[j];
            uint8_t bt = (uint8_t)(bt16 & 63u);
            int kap = __builtin_parity((unsigned)(m & row));
            G.alpha = al; G.beta = bt; G.nl = lnl[i]; G.gidx = lgx[i];
            G.pad0 = 0; G.pad1 = 0;
            if (al) {
                int pv = 31 - __builtin_clz((unsigned)al);
                G.pvmask = (uint8_t)(1u << pv);
                G.row_lane = (uint8_t)(row & 63u);
                uint64_t sg = 0;
                for (int r = 0; r < 64; ++r) {
                    int s = __builtin_parity((unsigned)(Brc[r] & row));
                    if ((r >> pv) & 1) s ^= (kap ^ 1);
                    sg |= (uint64_t)(s & 1) << r;
                }
                G.sgn = sg;
            } else {
                int pvb = 31 - __builtin_clz((unsigned)bt);
                G.pvmask = 0;
                uint8_t rl = (uint8_t)(row & 63u);
                if (kap ^ 1) rl = (uint8_t)(rl ^ (1u << pvb));
                G.row_lane = rl;
                uint64_t sg = 0;
                for (int r = 0; r < 64; ++r) {
                    int s = __builtin_parity((unsigned)(Brc[r] & row));
                    sg |= (uint64_t)(s & 1) << r;
                }
                G.sgn = sg;
            }
        }
        // ---- natural -> B permutation ops (used by pass 0) ----
        {
            bool vis[64]{}; int nt = 0;
            for (int r0 = 0; r0 < 64; ++r0) {
                if (vis[r0]) continue;
                int chain[64]{}; int k = 0; int r = r0;
                do { chain[k++] = r; vis[r] = true; r = (int)(Brc[r] >> 6); } while (r != r0);
                if (k == 1) {
                    uint8_t lx = (uint8_t)(Brc[r0] & 63u);
                    if (lx) { M.tops[nt].dst = (uint8_t)r0; M.tops[nt].src = (uint8_t)r0;
                              M.tops[nt].lx = lx; M.tops[nt].flags = 0; ++nt; }
                    continue;
                }
                M.tops[nt].dst = (uint8_t)chain[0]; M.tops[nt].src = (uint8_t)chain[1];
                M.tops[nt].lx = (uint8_t)(Brc[chain[0]] & 63u); M.tops[nt].flags = 1; ++nt;
                for (int i2 = 1; i2 < k - 1; ++i2) {
                    M.tops[nt].dst = (uint8_t)chain[i2]; M.tops[nt].src = (uint8_t)chain[i2 + 1];
                    M.tops[nt].lx = (uint8_t)(Brc[chain[i2]] & 63u); M.tops[nt].flags = 0; ++nt;
                }
                M.tops[nt].dst = (uint8_t)chain[k - 1]; M.tops[nt].src = 0;
                M.tops[nt].lx = (uint8_t)(Brc[chain[k - 1]] & 63u); M.tops[nt].flags = 2; ++nt;
            }
            M.ntops = nt;
        }
        // ---- measurement masks ----
        {
            uint16_t r = 0; uint8_t nl = 0;
            for (int w = 0; w < 16; ++w)
                if (((Rmeas >> w) & 1) && packedOfWire[w] >= 0)
                    r |= (uint16_t)(1u << packedOfWire[w]);
            for (int k = 0; k < 4; ++k)
                if ((Rmeas >> gw[k]) & 1) nl |= (uint8_t)(1u << k);
            M.meas_row = r; M.meas_nl = nl;
            uint64_t ms = 0;
            for (int rr = 0; rr < 64; ++rr)
                ms |= (uint64_t)(__builtin_parity((unsigned)(Brc[rr] & r)) & 1) << rr;
            M.measSgn = ms;
        }
    }
    S.np = np;
    return S;
}

constexpr Sched SCHED = build_sched();

// ---------------- device ----------------
typedef _Float16 h2 __attribute__((ext_vector_type(2)));

__device__ __forceinline__ float2 cmul2(float2 a, float2 b) {
    return make_float2(a.x * b.x - a.y * b.y, a.x * b.y + a.y * b.x);
}
__device__ __forceinline__ h2 pkfma(h2 a, h2 b, h2 c) {
    return __builtin_bit_cast(h2, __hfma2(__builtin_bit_cast(__half2, a),
                                          __builtin_bit_cast(__half2, b),
                                          __builtin_bit_cast(__half2, c)));
}
__device__ __forceinline__ h2 h2x(h2 a, unsigned m) {
    return __builtin_bit_cast(h2, __builtin_bit_cast(unsigned, a) ^ m);
}
__device__ __forceinline__ h2 bch2(unsigned u) { return __builtin_bit_cast(h2, u); }
__device__ __forceinline__ unsigned bcu(h2 a) { return __builtin_bit_cast(unsigned, a); }
__device__ __forceinline__ float xorf(float a, unsigned s) {
    return __uint_as_float(__float_as_uint(a) ^ s);
}
__device__ __forceinline__ unsigned pkh2(float lo, float hi) {
    h2 v; v.x = (_Float16)lo; v.y = (_Float16)hi;
    return __builtin_bit_cast(unsigned, v);
}
__device__ __forceinline__ unsigned bperm(unsigned addr, unsigned src) {
    return (unsigned)__builtin_amdgcn_ds_bpermute((int)addr, (int)src);
}

// Universal element rotation (block 1 of the R2-verified pair_rot):
// returns new value for `own` given partner `prt`:
//   new_re = ar*o_r - TAI*o_i + TBR*p_r - bi*p_i
//   new_im = ar*o_i + TAI*o_r + TBR*p_i + bi*p_r
__device__ __forceinline__ unsigned half_rot(unsigned AR, unsigned AIt,
    unsigned own, unsigned BRt, unsigned prt, unsigned BI)
{
    unsigned a;
    asm("v_pk_mul_f16 %0, %1, %3\n\t"
        "v_pk_fma_f16 %0, %2, %3, %0 op_sel:[0,1,0] op_sel_hi:[1,0,1] neg_lo:[1,0,0]\n\t"
        "v_pk_fma_f16 %0, %4, %5, %0\n\t"
        "v_pk_fma_f16 %0, %6, %5, %0 op_sel:[0,1,0] op_sel_hi:[1,0,1] neg_lo:[1,0,0]"
        : "=&v"(a)
        : "v"(AR), "v"(AIt), "v"(own), "v"(BRt), "v"(prt), "v"(BI));
    return a;
}

// Fused U = Rz(t2)Ry(t1)Rz(t0)Rx(enc), enc = 2*atan(x).
__global__ __launch_bounds__(512)
void precompute_kernel(const float* __restrict__ X, const float* __restrict__ Wt,
                       const float* __restrict__ Bs, uint4* __restrict__ Ug,
                       float* __restrict__ out)
{
    int id = blockIdx.x * 512 + threadIdx.x;
    if (id >= 512 * 64) return;
    int b = id >> 6, lw = id & 63, l = lw >> 4, w = lw & 15;
    float x  = X[b * 16 + w];
    float ce = 1.0f / sqrtf(1.0f + x * x);
    float se = x * ce;
    float t0 = 0.5f * Wt[(l * 16 + w) * 3 + 0];
    float t1 = 0.5f * Wt[(l * 16 + w) * 3 + 1];
    float t2 = 0.5f * Wt[(l * 16 + w) * 3 + 2];
    float c1 = cosf(t1), s1 = sinf(t1);
    float ca = cosf(t0 + t2), sa = sinf(t0 + t2);
    float cb = cosf(t2 - t0), sb = sinf(t2 - t0);
    float2 W00 = make_float2( c1 * ca, -c1 * sa);
    float2 W01 = make_float2(-s1 * cb,  s1 * sb);
    float2 a  = make_float2(W00.x * ce + W01.y * se, W00.y * ce - W01.x * se);
    float2 bb = make_float2(W00.y * se + W01.x * ce, -W00.x * se + W01.y * ce);
    uint4 o;
    o.x = pkh2(a.x,  a.x);
    o.y = pkh2(a.y,  a.y);
    o.z = pkh2(bb.x, bb.x);
    o.w = pkh2(bb.y, bb.y);
    Ug[id] = o;
    if (lw == 0) out[b] = Bs[0];
}

// Pass P: one wave per (batch, chunk) tile; 64 amps/lane in VGPRs.
template <int P>
__global__ __launch_bounds__(64, 4)
void pass_kernel(const uint4* __restrict__ Ug, unsigned* __restrict__ state,
                 float* __restrict__ out)
{
    static constexpr PassR M = SCHED.ps[P];
    constexpr int NP   = SCHED.np;
    constexpr int MODE = (P == 0) ? 0 : ((P == NP - 1) ? 2 : 1);

    const unsigned lane = threadIdx.x;
    const unsigned lane4 = lane << 2;
    const int bb  = blockIdx.x >> 4;
    const unsigned c = blockIdx.x & 15u;
    const uint4* __restrict__ Ugb = Ug + (size_t)bb * 64;
    unsigned* __restrict__ stp = state + ((size_t)bb << 16);

    unsigned cIns = 0;
    #pragma unroll
    for (int k = 0; k < 4; ++k) cIns |= ((c >> k) & 1u) << M.gap[k];

    unsigned v[64];

    if constexpr (MODE == 0) {
        // product state in natural coords: kv (chunk+lane factors, f32), then
        // in-register fp16 butterfly over the 6 reg bits.
        float2 kv = make_float2(1.f, 0.f);
        #pragma unroll
        for (int t = 0; t < 4; ++t) {
            uint4 u = Ugb[M.nlw[t]];
            float ar = (float)bch2(u.x).x, ai = (float)bch2(u.y).x;
            float br = (float)bch2(u.z).x, bi = (float)bch2(u.w).x;
            float2 col = ((c >> t) & 1u) ? make_float2(-br, bi)
                                         : make_float2(ar, ai);
            kv = cmul2(kv, col);
        }
        #pragma unroll
        for (int b = 0; b < 6; ++b) {
            uint4 u = Ugb[M.wire_of_bit[b]];
            float ar = (float)bch2(u.x).x, ai = (float)bch2(u.y).x;
            float br = (float)bch2(u.z).x, bi = (float)bch2(u.w).x;
            float2 col = ((lane >> b) & 1u) ? make_float2(-br, bi)
                                            : make_float2(ar, ai);
            kv = cmul2(kv, col);
        }
        v[0] = pkh2(kv.x, kv.y);
        #pragma unroll
        for (int b = 0; b < 6; ++b) {
            uint4 cf = Ugb[M.wire_of_bit[6 + b]];
            const h2 AR2  = bch2(cf.x);
            const h2 AIpm = h2x(bch2(cf.y), 0x00008000u);
            const h2 BRn  = h2x(bch2(cf.z), 0x80008000u);
            const h2 BIpm = h2x(bch2(cf.w), 0x00008000u);
            #pragma unroll
            for (int t = 0; t < (1 << b); ++t) {
                h2 a = bch2(v[t]);
                h2 sw = a.yx;
                v[t | (1 << b)] = bcu(pkfma(BRn, a, BIpm * sw));
                v[t]            = bcu(pkfma(AR2, a, AIpm * sw));
            }
        }
        // permute natural -> B coords (cycle walk, 1 temp)
        unsigned tmp = 0;
        #pragma unroll
        for (int i = 0; i < M.ntops; ++i) {
            const TOp o = M.tops[i];
            unsigned sv = (o.flags & 2) ? tmp : v[o.src];
            if (o.flags & 1) tmp = v[o.dst];
            v[o.dst] = o.lx ? bperm(lane4 ^ ((unsigned)o.lx << 2), sv) : sv;
        }
    } else {
        #pragma unroll
        for (int r = 0; r < 64; ++r)
            v[r] = stp[((unsigned)M.EB[r] ^ cIns) ^ lane];
    }

    #pragma unroll
    for (int gi = 0; gi < M.ngates; ++gi) {
        const GateR G = M.g[gi];
        const uint4 cf = Ugb[G.gidx];
        const unsigned lp = ((unsigned)__popc(lane & (unsigned)G.row_lane) +
                             (unsigned)__popc((unsigned)G.nl & c)) & 1u;
        const unsigned gm = lp ? 0x80008000u : 0u;
        const unsigned AR  = cf.x;
        const unsigned BI  = cf.w;
        const unsigned AIg = cf.y ^ gm, AIf = AIg ^ 0x80008000u;
        const unsigned BRg = cf.z ^ gm, BRf = BRg ^ 0x80008000u;
        const unsigned pa  = lane4 ^ ((unsigned)G.beta << 2);
        if (G.alpha) {
            #pragma unroll
            for (int r = 0; r < 64; ++r) {
                if (r & G.pvmask) continue;          // p-side reps only
                const int q = r ^ G.alpha;
                unsigned prtP, prtQ;
                if (G.beta) { prtP = bperm(pa, v[q]); prtQ = bperm(pa, v[r]); }
                else        { prtP = v[q];            prtQ = v[r]; }
                const bool sr = (G.sgn >> r) & 1, sq = (G.sgn >> q) & 1;
                const unsigned nr = half_rot(AR, sr ? AIf : AIg, v[r],
                                             sr ? BRf : BRg, prtP, BI);
                const unsigned nq = half_rot(AR, sq ? AIf : AIg, v[q],
                                             sq ? BRf : BRg, prtQ, BI);
                v[r] = nr; v[q] = nq;
            }
        } else {
            #pragma unroll
            for (int r = 0; r < 64; ++r) {
                const unsigned prt = bperm(pa, v[r]);
                const bool sr = (G.sgn >> r) & 1;
                v[r] = half_rot(AR, sr ? AIf : AIg, v[r],
                                sr ? BRf : BRg, prt, BI);
            }
        }
    }

    if constexpr (MODE == 2) {
        float acc = 0.f;
        const unsigned mp = ((unsigned)__popc(lane & ((unsigned)M.meas_row & 63u)) +
                             (unsigned)__popc((unsigned)M.meas_nl & c)) & 1u;
        const unsigned mb = mp << 31;
        #pragma unroll
        for (int r = 0; r < 64; ++r) {
            h2 a = bch2(v[r]);
            float vr = (float)a.x, vi = (float)a.y;
            float pr = __builtin_fmaf(vr, vr, vi * vi);
            const unsigned st = (unsigned)((M.measSgn >> r) & 1u) << 31;
            acc += xorf(pr, mb ^ st);
        }
        for (int off = 32; off > 0; off >>= 1) acc += __shfl_down(acc, off, 64);
        if (lane == 0) atomicAdd(&out[bb], acc);
    } else {
        #pragma unroll
        for (int r = 0; r < 64; ++r)
            stp[((unsigned)M.EB[r] ^ cIns) ^ lane] = v[r];
    }
}

extern "C" void kernel_launch(void* const* d_in, const int* in_sizes, int n_in,
                              void* d_out, int out_size, void* d_ws, size_t ws_size,
                              hipStream_t stream)
{
    const float* X  = (const float*)d_in[0];
    const float* Wt = (const float*)d_in[1];
    const float* Bs = (const float*)d_in[2];
    float* out = (float*)d_out;

    const size_t UG_BYTES = (size_t)512 * 64 * sizeof(uint4);  // 512 KiB
    uint4*    Ug    = (uint4*)d_ws;
    unsigned* state = (unsigned*)((char*)d_ws + UG_BYTES);
    size_t avail = ws_size > UG_BYTES ? ws_size - UG_BYTES : 0;
    int group = 1;   // fp16 state: 256 KiB per batch element
    while (group < 512 && (size_t)(group * 2) * 262144ull <= avail)
        group <<= 1;
    const int ngroups = 512 / group;

    constexpr int NP = SCHED.np;

    precompute_kernel<<<dim3(64), dim3(512), 0, stream>>>(X, Wt, Bs, Ug, out);
    for (int g = 0; g < ngroups; ++g) {
        const uint4* ug = Ug + (size_t)g * group * 64;
        float* og = out + (size_t)g * group;
        dim3 grid((unsigned)(group << 4));
        for (int p = 0; p < NP; ++p) {
            switch (p) {
            case 0: pass_kernel<0><<<grid, dim3(64), 0, stream>>>(ug, state, og); break;
            case 1: pass_kernel<1><<<grid, dim3(64), 0, stream>>>(ug, state, og); break;
            case 2: pass_kernel<2><<<grid, dim3(64), 0, stream>>>(ug, state, og); break;
            case 3: pass_kernel<3><<<grid, dim3(64), 0, stream>>>(ug, state, og); break;
            case 4: pass_kernel<4><<<grid, dim3(64), 0, stream>>>(ug, state, og); break;
            case 5: pass_kernel<5><<<grid, dim3(64), 0, stream>>>(ug, state, og); break;
            case 6: pass_kernel<6><<<grid, dim3(64), 0, stream>>>(ug, state, og); break;
            case 7: pass_kernel<7><<<grid, dim3(64), 0, stream>>>(ug, state, og); break;
            }
        }
    }

    (void)in_sizes; (void)n_in; (void)out_size; (void)ws_size;
}

// Round 8
// 330.137 us; speedup vs baseline: 6.4256x; 6.4256x over previous
//
#include <hip/hip_runtime.h>
#include <hip/hip_fp16.h>
#include <cstdint>
#include <cstring>

// VQR circuit simulator: 16 qubits, B=512, 4 layers.
// CNOTs are GF(2) index-relabeling bookkeeping. Fused 1q gates (SU(2)) are
// XOR-mask pair rotations. The ENTIRE gate schedule is computed at COMPILE
// TIME (constexpr) and baked in as immediates (R3). R4: mega-bundles with
// in-span register absorption + direct f32 product-state init for MODE0.
// NEW vs R4: COMMUTE-AWARE BUNDLE PACKING -- a gate whose mask lies in the
// current bundle's rank-4 span is hoisted into the bundle past skipped
// gates whenever it commutes with all of them (same legality rule the pass
// scheduler uses). Packs more gates/bundle -> fewer LDS round-trips and
// barriers per pass. Pair update is inline VOP3P asm (8 packed ops/pair),
// fp16 end-to-end.

struct GateC {
    uint16_t row;    // local R mask (sign)
    uint16_t flip;   // per-t p-side sign bit = parity(voff[t] & row)
    uint8_t  mt;     // pair mask in t-space (compile-time)
    uint8_t  nl;     // chunk-bit R mask
    uint8_t  gidx;   // coefficient index l*16+w
    uint8_t  pad;
};

struct BundleMeta {
    uint16_t voff[16];   // coset offsets (local 12-bit index space)
    uint8_t  piv[4];     // pivot bit positions, ASCENDING (rep expansion)
    uint8_t  ngates;
    uint8_t  pad[3];
    GateC    gc[24];
};

struct PassMeta {
    int       nbundles;
    BundleMeta bd[12];
    uint8_t   gap[4];          // non-local bit positions, ASCENDING (all >=8)
    uint8_t   nlw[4];          // chunk bit k -> wire
    uint8_t   wire_of_bit[12]; // packed LDS bit -> wire (product-state init)
    uint16_t  meas_row;        // measurement parity mask (local bits)
    uint8_t   meas_nl;         // measurement parity mask (chunk bits)
};

struct Sched { int np; PassMeta pms[8]; };

// ---------------- compile-time schedule builder ----------------
constexpr Sched build_sched() {
    Sched S{};
    const int MAXP = 8;
    uint16_t D[16]{}, R[16]{};
    for (int w = 0; w < 16; ++w) { D[w] = R[w] = (uint16_t)(1u << w); }
    uint16_t gD[48]{}, gR[48]{}; uint8_t ggi[48]{}; bool gk[48]{};
    int ng = 0;
    for (int l = 1; l <= 3; ++l) {
        for (int w = 0; w < 16; ++w) { int t = (w + 1) & 15; D[w] ^= D[t]; R[t] ^= R[w]; }
        for (int w = 0; w < 16; ++w) {
            gD[ng] = D[w]; gR[ng] = R[w]; ggi[ng] = (uint8_t)(l * 16 + w);
            gk[ng] = true; ++ng;
        }
    }
    for (int w = 0; w < 16; ++w) { int t = (w + 1) & 15; D[w] ^= D[t]; R[t] ^= R[w]; }
    const uint16_t Rmeas = R[0];
    {   // backward prune
        uint16_t keptD[49]{}, keptR[49]{}; int nk = 0;
        keptD[nk] = 0; keptR[nk] = Rmeas; ++nk;
        for (int i = ng - 1; i >= 0; --i) {
            bool comm = true;
            for (int k = 0; k < nk; ++k) {
                if (__builtin_parity((unsigned)(gD[i] & keptR[k])) ||
                    __builtin_parity((unsigned)(keptD[k] & gR[i]))) { comm = false; break; }
            }
            if (comm) gk[i] = false;
            else { keptD[nk] = gD[i]; keptR[nk] = gR[i]; ++nk; }
        }
    }
    int nkept = 0; unsigned long long keptM = 0;
    for (int i = 0; i < ng; ++i) if (gk[i]) { ++nkept; keptM |= 1ull << i; }
    unsigned long long cm[48]{};
    for (int i = 0; i < ng; ++i)
        for (int j = 0; j < ng; ++j)
            if (!(__builtin_parity((unsigned)(gD[i] & gR[j])) ||
                  __builtin_parity((unsigned)(gD[j] & gR[i]))))
                cm[i] |= 1ull << j;
    int passOf[48]{};
    for (int i = 0; i < ng; ++i) passOf[i] = -1;
    auto bitsim = [&](uint16_t SA_, uint16_t SB_, int maxnp, int* po) -> int {
        unsigned long long sc = 0; int rem = nkept, npp = 0, stall = 0;
        while (rem > 0 && npp < MAXP) {
            uint16_t Sm = (npp & 1) ? SB_ : SA_;
            int got = 0;
            for (int i = 0; i < ng; ++i) {
                unsigned long long bi = 1ull << i;
                if (!(keptM & bi) || (sc & bi)) continue;
                if (gD[i] & Sm) continue;
                unsigned long long prior = keptM & ~sc & (bi - 1ull);
                if (prior & ~cm[i]) continue;
                sc |= bi; --rem; ++got;
                if (po) po[i] = npp;
            }
            ++npp;
            if (!got) { if (++stall >= 2) break; } else stall = 0;
            if (rem > 0 && npp >= maxnp) return 99;
        }
        return rem == 0 ? npp : 99;
    };
    int bestA = -1, bestB = 0;
    for (int target = 2; target <= MAXP && bestA < 0; ++target)
        for (int a = 0; a < 16 && bestA < 0; ++a)
            for (int b = 0; b < 16; ++b) {
                uint16_t SA_ = 0, SB_ = 0;
                for (int k = 0; k < 4; ++k) {
                    SA_ |= (uint16_t)(1u << ((a + k) & 15));
                    SB_ |= (uint16_t)(1u << ((b + k) & 15));
                }
                int rv = bitsim(SA_, SB_, target, nullptr);
                if (rv <= target) { bestA = a; bestB = b; break; }
            }
    if (bestA < 0) { bestA = 0; bestB = 8; }
    uint16_t SA = 0, SB = 0;
    int exA[4]{}, exB[4]{};
    for (int k = 0; k < 4; ++k) {
        exA[k] = (bestA + k) & 15; exB[k] = (bestB + k) & 15;
        SA |= (uint16_t)(1u << exA[k]); SB |= (uint16_t)(1u << exB[k]);
    }
    int np = bitsim(SA, SB, MAXP, passOf);
    if (np > MAXP) np = MAXP;
    if (np < 2) np = 2;
    int wireToPos[16]{}; bool used[16]{};
    int pos = 15;
    for (int k = 0; k < 4; ++k) { wireToPos[exA[k]] = pos--; used[exA[k]] = true; }
    for (int k = 0; k < 4; ++k)
        if (!used[exB[k]]) { wireToPos[exB[k]] = pos--; used[exB[k]] = true; }
    for (int w = 0; w < 16; ++w) if (!used[w]) wireToPos[w] = pos--;
    int posToWire[16]{};
    for (int w = 0; w < 16; ++w) posToWire[wireToPos[w]] = w;
    for (int p = 0; p < np; ++p) {
        PassMeta& M = S.pms[p];
        const int* ex = (p & 1) ? exB : exA;
        int gp[4]{}, gw[4]{};
        for (int k = 0; k < 4; ++k) { gp[k] = wireToPos[ex[k]]; gw[k] = ex[k]; }
        for (int a2 = 0; a2 < 4; ++a2)
            for (int b2 = a2 + 1; b2 < 4; ++b2)
                if (gp[b2] < gp[a2]) {
                    int t = gp[a2]; gp[a2] = gp[b2]; gp[b2] = t;
                    t = gw[a2]; gw[a2] = gw[b2]; gw[b2] = t;
                }
        for (int k = 0; k < 4; ++k) { M.gap[k] = (uint8_t)gp[k]; M.nlw[k] = (uint8_t)gw[k]; }
        int packedOfWire[16]{};
        for (int w = 0; w < 16; ++w) packedOfWire[w] = -1;
        int t = 0;
        for (int q = 0; q < 16; ++q) {
            bool isgap = false;
            for (int k = 0; k < 4; ++k) if (q == gp[k]) isgap = true;
            if (isgap) continue;
            M.wire_of_bit[t] = (uint8_t)posToWire[q];
            packedOfWire[posToWire[q]] = t;
            ++t;
        }
        uint16_t lm[48]{}, lr[48]{}; uint8_t lnl[48]{}, lgx[48]{}; int nsel = 0;
        for (int i = 0; i < ng; ++i) {
            if (!gk[i] || passOf[i] != p) continue;
            uint16_t m = 0, r = 0; uint8_t nl = 0;
            for (int w = 0; w < 16; ++w) {
                if ((gD[i] >> w) & 1) m |= (uint16_t)(1u << packedOfWire[w]);
                if (((gR[i] >> w) & 1) && packedOfWire[w] >= 0)
                    r |= (uint16_t)(1u << packedOfWire[w]);
            }
            for (int k = 0; k < 4; ++k)
                if ((gR[i] >> gw[k]) & 1) nl |= (uint8_t)(1u << k);
            lm[nsel] = m; lr[nsel] = r; lnl[nsel] = nl; lgx[nsel] = ggi[i]; ++nsel;
        }
        // ---- commute-aware mega-bundling: rank-4 span, forward cherry-pick.
        // A gate may be hoisted into the current bundle past skipped gates iff
        // it commutes with every skipped (not-yet-executed) earlier gate.
        // D masks are window-local, so parity(lm_i & lr_j) is the exact
        // commutator parity.
        M.nbundles = 0;
        bool done[48]{};
        int ndone = 0;
        while (ndone < nsel && M.nbundles < 12) {
            BundleMeta& B = M.bd[M.nbundles]; ++M.nbundles;
            uint16_t om[4]{}, red[4]{}; int pv[4]{}; uint8_t comb[4]{};
            int rank = 0, ngate = 0;
            for (int i = 0; i < nsel && ngate < 24; ++i) {
                if (done[i]) continue;
                uint16_t x = lm[i]; uint8_t rep = 0;
                for (int j = 0; j < rank; ++j)
                    if ((x >> pv[j]) & 1) { x ^= red[j]; rep ^= comb[j]; }
                if (x != 0 && rank >= 4) continue;     // doesn't fit this bundle
                bool ok = true;                        // legal to hoist?
                for (int j = 0; j < i && ok; ++j) {
                    if (done[j]) continue;
                    if (__builtin_parity((unsigned)(lm[i] & lr[j])) ||
                        __builtin_parity((unsigned)(lm[j] & lr[i]))) ok = false;
                }
                if (!ok) continue;
                if (x != 0) {                          // extend basis
                    om[rank] = lm[i]; red[rank] = x;
                    pv[rank] = 31 - __builtin_clz((unsigned)x);
                    comb[rank] = (uint8_t)((1u << rank) | rep);
                    B.gc[ngate].mt = (uint8_t)(1u << rank);
                    ++rank;
                } else {                               // in-span: free in-register
                    B.gc[ngate].mt = rep;
                }
                B.gc[ngate].row = lr[i]; B.gc[ngate].nl = lnl[i];
                B.gc[ngate].gidx = lgx[i];
                ++ngate; done[i] = true; ++ndone;
            }
            B.ngates = (uint8_t)ngate;
            for (int b = 11; b >= 0 && rank < 4; --b) {   // pad basis
                uint16_t x = (uint16_t)(1u << b);
                for (int j = 0; j < rank; ++j)
                    if ((x >> pv[j]) & 1) x ^= red[j];
                if (!x) continue;
                om[rank] = (uint16_t)(1u << b); red[rank] = x;
                pv[rank] = 31 - __builtin_clz((unsigned)x);
                ++rank;
            }
            for (int tt = 0; tt < 16; ++tt) {
                uint16_t v = 0;
                for (int j = 0; j < 4; ++j) if ((tt >> j) & 1) v ^= om[j];
                B.voff[tt] = v;
            }
            for (int g2 = 0; g2 < ngate; ++g2) {
                uint16_t f = 0;
                for (int tt = 0; tt < 16; ++tt)
                    if (__builtin_parity((unsigned)(B.voff[tt] & B.gc[g2].row)))
                        f |= (uint16_t)(1u << tt);
                B.gc[g2].flip = f;
            }
            int sp[4] = {pv[0], pv[1], pv[2], pv[3]};
            for (int a2 = 0; a2 < 4; ++a2)
                for (int b2 = a2 + 1; b2 < 4; ++b2)
                    if (sp[b2] < sp[a2]) { int tt = sp[a2]; sp[a2] = sp[b2]; sp[b2] = tt; }
            for (int j = 0; j < 4; ++j) B.piv[j] = (uint8_t)sp[j];
        }
        {   // measurement masks
            uint16_t r = 0; uint8_t nl = 0;
            for (int w = 0; w < 16; ++w)
                if (((Rmeas >> w) & 1) && packedOfWire[w] >= 0)
                    r |= (uint16_t)(1u << packedOfWire[w]);
            for (int k = 0; k < 4; ++k)
                if ((Rmeas >> gw[k]) & 1) nl |= (uint8_t)(1u << k);
            M.meas_row = r; M.meas_nl = nl;
        }
    }
    S.np = np;
    return S;
}

constexpr Sched SCHED = build_sched();

// ---------------- device ----------------
typedef _Float16 h2 __attribute__((ext_vector_type(2)));

__device__ __forceinline__ float2 cmul2(float2 a, float2 b) {
    return make_float2(a.x * b.x - a.y * b.y, a.x * b.y + a.y * b.x);
}
__device__ __forceinline__ h2 pkfma(h2 a, h2 b, h2 c) {
    return __builtin_bit_cast(h2, __hfma2(__builtin_bit_cast(__half2, a),
                                          __builtin_bit_cast(__half2, b),
                                          __builtin_bit_cast(__half2, c)));
}
__device__ __forceinline__ h2 h2x(h2 a, unsigned m) {
    return __builtin_bit_cast(h2, __builtin_bit_cast(unsigned, a) ^ m);
}
__device__ __forceinline__ h2 bch2(unsigned u) { return __builtin_bit_cast(h2, u); }
__device__ __forceinline__ float xorf(float a, unsigned s) {
    return __uint_as_float(__float_as_uint(a) ^ s);
}
__device__ __forceinline__ unsigned pkh2(float lo, float hi) {
    h2 v; v.x = (_Float16)lo; v.y = (_Float16)hi;
    return __builtin_bit_cast(unsigned, v);
}

// Pair rotation, exact VOP3P codegen (verified R2/R3/R4). (re,im)=(lo,hi).
__device__ __forceinline__ void pair_rot(unsigned& np_, unsigned& nq_,
    unsigned p, unsigned q, unsigned AR, unsigned AIt, unsigned BRt, unsigned BI)
{
    unsigned a, b;
    asm("v_pk_mul_f16 %0, %1, %3\n\t"
        "v_pk_fma_f16 %0, %2, %3, %0 op_sel:[0,1,0] op_sel_hi:[1,0,1] neg_lo:[1,0,0]\n\t"
        "v_pk_fma_f16 %0, %4, %5, %0\n\t"
        "v_pk_fma_f16 %0, %6, %5, %0 op_sel:[0,1,0] op_sel_hi:[1,0,1] neg_lo:[1,0,0]"
        : "=&v"(a)
        : "v"(AR), "v"(AIt), "v"(p), "v"(BRt), "v"(q), "v"(BI));
    asm("v_pk_mul_f16 %0, %1, %5\n\t"
        "v_pk_fma_f16 %0, %2, %5, %0 op_sel:[0,1,0] op_sel_hi:[1,0,1] neg_hi:[1,0,0]\n\t"
        "v_pk_fma_f16 %0, %4, %3, %0 neg_lo:[1,0,0] neg_hi:[1,0,0]\n\t"
        "v_pk_fma_f16 %0, %6, %3, %0 op_sel:[0,1,0] op_sel_hi:[1,0,1] neg_lo:[1,0,0]"
        : "=&v"(b)
        : "v"(AR), "v"(AIt), "v"(p), "v"(BRt), "v"(q), "v"(BI));
    np_ = a; nq_ = b;
}

// Fused U = Rz(t2)Ry(t1)Rz(t0)Rx(enc), enc = 2*atan(x).
__global__ __launch_bounds__(512)
void precompute_kernel(const float* __restrict__ X, const float* __restrict__ Wt,
                       const float* __restrict__ Bs, uint4* __restrict__ Ug,
                       float* __restrict__ out)
{
    int id = blockIdx.x * 512 + threadIdx.x;
    if (id >= 512 * 64) return;
    int b = id >> 6, lw = id & 63, l = lw >> 4, w = lw & 15;
    float x  = X[b * 16 + w];
    float ce = 1.0f / sqrtf(1.0f + x * x);
    float se = x * ce;
    float t0 = 0.5f * Wt[(l * 16 + w) * 3 + 0];
    float t1 = 0.5f * Wt[(l * 16 + w) * 3 + 1];
    float t2 = 0.5f * Wt[(l * 16 + w) * 3 + 2];
    float c1 = cosf(t1), s1 = sinf(t1);
    float ca = cosf(t0 + t2), sa = sinf(t0 + t2);
    float cb = cosf(t2 - t0), sb = sinf(t2 - t0);
    float2 W00 = make_float2( c1 * ca, -c1 * sa);
    float2 W01 = make_float2(-s1 * cb,  s1 * sb);
    float2 a  = make_float2(W00.x * ce + W01.y * se, W00.y * ce - W01.x * se);
    float2 bb = make_float2(W00.y * se + W01.x * ce, -W00.x * se + W01.y * ce);
    uint4 o;
    o.x = pkh2(a.x,  a.x);
    o.y = pkh2(a.y,  a.y);
    o.z = pkh2(bb.x, bb.x);
    o.w = pkh2(bb.y, bb.y);
    Ug[id] = o;
    if (lw == 0) out[b] = Bs[0];
}

// Pass P of the compile-time schedule.
template <int P>
__global__ __launch_bounds__(256, 8)
void pass_kernel(const uint4* __restrict__ Ug, unsigned* __restrict__ state,
                 float* __restrict__ out)
{
    static constexpr PassMeta M = SCHED.pms[P];
    constexpr int NP   = SCHED.np;
    constexpr int MODE = (P == 0) ? 0 : ((P == NP - 1) ? 2 : 1);

    __shared__ __align__(16) unsigned amp[4096];   // 16 KiB
    __shared__ uint4 coef[64];
    const int tid = threadIdx.x;
    const int bb  = blockIdx.x >> 4;
    const unsigned c = blockIdx.x & 15u;
    const size_t base = (size_t)bb << 16;
    if (tid < 64) coef[tid] = Ug[(size_t)bb * 64 + tid];

    auto expand = [&](unsigned x) -> unsigned {   // gaps ascending, all >= 8
        #pragma unroll
        for (int k = 0; k < 4; ++k) {
            const unsigned g = M.gap[k];
            x = ((x >> g) << (g + 1)) | (x & ((1u << g) - 1u)) | (((c >> k) & 1u) << g);
        }
        return x;
    };

    if constexpr (MODE == 0) {
        __syncthreads();   // coef ready
        // product state: chunk factor x bits 0..7 directly in f32 registers
        float2 kv = make_float2(1.f, 0.f);
        #pragma unroll
        for (int t = 0; t < 4; ++t) {
            uint4 u = coef[M.nlw[t]];
            float ar = (float)bch2(u.x).x, ai = (float)bch2(u.y).x;
            float br = (float)bch2(u.z).x, bi = (float)bch2(u.w).x;
            float2 col = ((c >> t) & 1u) ? make_float2(-br, bi)
                                         : make_float2(ar, ai);
            kv = cmul2(kv, col);
        }
        #pragma unroll
        for (int b = 0; b < 8; ++b) {
            uint4 u = coef[M.wire_of_bit[b]];
            float ar = (float)bch2(u.x).x, ai = (float)bch2(u.y).x;
            float br = (float)bch2(u.z).x, bi = (float)bch2(u.w).x;
            float2 col = (((unsigned)tid >> b) & 1u) ? make_float2(-br, bi)
                                                     : make_float2(ar, ai);
            kv = cmul2(kv, col);
        }
        amp[tid] = pkh2(kv.x, kv.y);
        __syncthreads();
        #pragma unroll
        for (int s = 8; s < 12; ++s) {
            const int n = 1 << s;
            uint4 cf = coef[M.wire_of_bit[s]];
            const h2 AR2  = bch2(cf.x);
            const h2 AIpm = h2x(bch2(cf.y), 0x00008000u);
            const h2 BRn  = h2x(bch2(cf.z), 0x80008000u);
            const h2 BIpm = h2x(bch2(cf.w), 0x00008000u);
            for (int i = tid; i < n; i += 256) {
                h2 a = bch2(amp[i]);
                h2 sw = a.yx;
                amp[i + n] = __builtin_bit_cast(unsigned, pkfma(BRn, a, BIpm * sw));
                amp[i]     = __builtin_bit_cast(unsigned, pkfma(AR2, a, AIpm * sw));
            }
            __syncthreads();
        }
    } else {
        #pragma unroll
        for (int it = 0; it < 4; ++it) {
            unsigned u = (unsigned)(tid + it * 256) * 4u;
            unsigned a = expand(u);
            uint4 v = *reinterpret_cast<const uint4*>(state + base + a);
            *reinterpret_cast<uint4*>(&amp[u]) = v;
        }
        __syncthreads();   // also covers coef staging
    }

    #pragma unroll
    for (int ci = 0; ci < M.nbundles; ++ci) {
        unsigned r = (unsigned)tid;
        #pragma unroll
        for (int k = 0; k < 4; ++k) {
            const unsigned p = M.bd[ci].piv[k];
            r = ((r >> p) << (p + 1)) | (r & ((1u << p) - 1u));
        }
        const unsigned rb = r << 2;
        unsigned a_[16];
        #pragma unroll
        for (int t = 0; t < 16; ++t)
            a_[t] = *(const unsigned*)((const char*)amp +
                     (rb ^ ((unsigned)M.bd[ci].voff[t] << 2)));
        #pragma unroll
        for (int gi = 0; gi < M.bd[ci].ngates; ++gi) {
            const uint4 cf = coef[M.bd[ci].gc[gi].gidx];
            const unsigned par =
                ((unsigned)__popc(r & (unsigned)M.bd[ci].gc[gi].row) +
                 (unsigned)__popc((unsigned)M.bd[ci].gc[gi].nl & c)) & 1u;
            const unsigned gm = par ? 0x80008000u : 0u;
            const unsigned AR  = cf.x;
            const unsigned BI  = cf.w;
            const unsigned AIg = cf.y ^ gm;
            const unsigned BRg = cf.z ^ gm;
            const unsigned AIf = AIg ^ 0x80008000u;
            const unsigned BRf = BRg ^ 0x80008000u;
            const int mt = M.bd[ci].gc[gi].mt;                       // compile-time
            const int mh = 1 << (31 - __builtin_clz((unsigned)mt));  // compile-time
            #pragma unroll
            for (int t = 0; t < 16; ++t) {
                if (t & mh) continue;
                const int t2 = t ^ mt;
                const bool FB = ((M.bd[ci].gc[gi].flip >> t) & 1u) != 0;
                unsigned np_, nq_;
                pair_rot(np_, nq_, a_[t], a_[t2], AR,
                         FB ? AIf : AIg, FB ? BRf : BRg, BI);
                a_[t] = np_; a_[t2] = nq_;
            }
        }
        if (MODE == 2 && ci == M.nbundles - 1) {
            // measure directly from registers (skip final LDS round-trip)
            float acc = 0.f;
            const unsigned sb = (((unsigned)__popc(r & (unsigned)M.meas_row) +
                                  (unsigned)__popc((unsigned)M.meas_nl & c)) & 1u) << 31;
            #pragma unroll
            for (int t = 0; t < 16; ++t) {
                h2 a = bch2(a_[t]);
                float vr = (float)a.x, vi = (float)a.y;
                float pr = __builtin_fmaf(vr, vr, vi * vi);
                const unsigned st =
                    __builtin_parity((unsigned)(M.bd[ci].voff[t] & M.meas_row))
                        ? 0x80000000u : 0u;   // compile-time
                acc += xorf(pr, sb ^ st);
            }
            for (int off = 32; off > 0; off >>= 1) acc += __shfl_down(acc, off, 64);
            if ((tid & 63) == 0) atomicAdd(&out[bb], acc);
            return;
        }
        #pragma unroll
        for (int t = 0; t < 16; ++t)
            *(unsigned*)((char*)amp + (rb ^ ((unsigned)M.bd[ci].voff[t] << 2))) = a_[t];
        __syncthreads();
    }

    if constexpr (MODE == 2) {
        // fallback (only if nbundles==0): measure from LDS
        float acc = 0.f;
        const unsigned mcp = (unsigned)(__popc((unsigned)M.meas_nl & c) & 1);
        for (int k = 0; k < 16; ++k) {
            unsigned u = (unsigned)(tid + k * 256);
            h2 a = bch2(amp[u]);
            float vr = (float)a.x, vi = (float)a.y;
            float pr = __builtin_fmaf(vr, vr, vi * vi);
            acc += (((unsigned)__popc(u & (unsigned)M.meas_row) & 1u) ^ mcp)
                 ? -pr : pr;
        }
        for (int off = 32; off > 0; off >>= 1) acc += __shfl_down(acc, off, 64);
        if ((tid & 63) == 0) atomicAdd(&out[bb], acc);
    } else {
        #pragma unroll
        for (int it = 0; it < 4; ++it) {
            unsigned u = (unsigned)(tid + it * 256) * 4u;
            unsigned ad = expand(u);
            uint4 v = *reinterpret_cast<const uint4*>(&amp[u]);
            *reinterpret_cast<uint4*>(state + base + ad) = v;
        }
    }
}

extern "C" void kernel_launch(void* const* d_in, const int* in_sizes, int n_in,
                              void* d_out, int out_size, void* d_ws, size_t ws_size,
                              hipStream_t stream)
{
    const float* X  = (const float*)d_in[0];
    const float* Wt = (const float*)d_in[1];
    const float* Bs = (const float*)d_in[2];
    float* out = (float*)d_out;

    const size_t UG_BYTES = (size_t)512 * 64 * sizeof(uint4);  // 512 KiB
    uint4*    Ug    = (uint4*)d_ws;
    unsigned* state = (unsigned*)((char*)d_ws + UG_BYTES);
    size_t avail = ws_size > UG_BYTES ? ws_size - UG_BYTES : 0;
    int group = 1;   // fp16 state: 256 KiB per batch element
    while (group < 512 && (size_t)(group * 2) * 262144ull <= avail)
        group <<= 1;
    const int ngroups = 512 / group;

    constexpr int NP = SCHED.np;

    precompute_kernel<<<dim3(64), dim3(512), 0, stream>>>(X, Wt, Bs, Ug, out);
    for (int g = 0; g < ngroups; ++g) {
        const uint4* ug = Ug + (size_t)g * group * 64;
        float* og = out + (size_t)g * group;
        dim3 grid((unsigned)(group << 4));
        for (int p = 0; p < NP; ++p) {
            switch (p) {
            case 0: pass_kernel<0><<<grid, dim3(256), 0, stream>>>(ug, state, og); break;
            case 1: pass_kernel<1><<<grid, dim3(256), 0, stream>>>(ug, state, og); break;
            case 2: pass_kernel<2><<<grid, dim3(256), 0, stream>>>(ug, state, og); break;
            case 3: pass_kernel<3><<<grid, dim3(256), 0, stream>>>(ug, state, og); break;
            case 4: pass_kernel<4><<<grid, dim3(256), 0, stream>>>(ug, state, og); break;
            case 5: pass_kernel<5><<<grid, dim3(256), 0, stream>>>(ug, state, og); break;
            case 6: pass_kernel<6><<<grid, dim3(256), 0, stream>>>(ug, state, og); break;
            case 7: pass_kernel<7><<<grid, dim3(256), 0, stream>>>(ug, state, og); break;
            }
        }
    }

    (void)in_sizes; (void)n_in; (void)out_size; (void)ws_size;
}